// Round 1
// baseline (693.858 us; speedup 1.0000x reference)
//
#include <hip/hip_runtime.h>

// Poly2d: out[b,o,h,w] = sum_{c,i,j} F[o,c,i,j] * s_i * s_j + bias[o]
// s = [1, 3x3 patch of x around (h,w), zero-padded], L = 10.
//
// Decomposition over the symmetric bilinear form (55 unique terms):
//   (0,0): constant 1 * F[o,c,0,0]            -> folded into bias_eff[o]
//   k=0..8   linear:  s_j     * (F[0,j]+F[j,0]),  j = k+1
//   k=9..17  square:  s_j^2   *  F[j,j],          j = k-8
//   k=18..53 pair:    s_i*s_j * (F[i,j]+F[j,i]),  1<=i<j<=9
// => GEMM  M=16384 pixels, K=64c*54, N=64 outputs, fp32 VALU (round 0).

#define NC   64
#define NO   64
#define KT   54   // symmetric terms per channel (excluding constant)

__device__ __forceinline__ void k_to_ij(int k, int& i, int& j) {
    if (k < 9)       { i = 0;     j = k + 1; }
    else if (k < 18) { i = k - 8; j = k - 8; }
    else {
        int t = k - 18;          // pairs (i<j), i,j in 1..9
        int ii = 1;
        while (t >= 9 - ii) { t -= 9 - ii; ++ii; }
        i = ii; j = ii + 1 + t;
    }
}

// Wt[(c*54 + k)*64 + o] = symmetrized filter weight
__global__ void prep_filters(const float* __restrict__ filters,
                             float* __restrict__ Wt) {
    int idx = blockIdx.x * blockDim.x + threadIdx.x;  // (c*54+k)*64+o
    int o = idx & 63;
    int k = (idx >> 6) % KT;
    int c = idx / (KT * NO);
    int i, j;
    k_to_ij(k, i, j);
    const float* Foc = filters + (size_t)(o * NC + c) * 100;
    float w = Foc[i * 10 + j];
    if (i != j) w += Foc[j * 10 + i];
    Wt[idx] = w;
}

// bias_eff[o] = biases[o] + sum_c F[o,c,0,0]
__global__ void prep_bias(const float* __restrict__ filters,
                          const float* __restrict__ biases,
                          float* __restrict__ bias_eff) {
    int o = threadIdx.x;
    float s = biases[o];
    for (int c = 0; c < NC; ++c)
        s += filters[(size_t)(o * NC + c) * 100];
    bias_eff[o] = s;
}

// One block per (b,h) row: 64 pixels x 64 outputs. 256 threads.
// Thread (og = tid&15, pg = tid>>4) owns o = og*4+[0..3], p = pg*4+[0..3].
__global__ __launch_bounds__(256) void poly2d_main(
        const float* __restrict__ x, const float* __restrict__ Wt,
        const float* __restrict__ bias_eff, float* __restrict__ out) {
    const int bh = blockIdx.x;            // b*64 + h
    const int b  = bh >> 6;
    const int h  = bh & 63;
    const int tid = threadIdx.x;
    const int og = tid & 15;
    const int pg = tid >> 4;

    __shared__ float xs[3][66];           // rows h-1..h+1, cols w=-1..64
    __shared__ float q[KT][64];           // per-channel products, all 64 pixels

    float acc[4][4] = {};

    for (int c = 0; c < NC; ++c) {
        __syncthreads();   // previous iteration done reading xs/q
        // ---- stage 3 input rows (zero-padded) for this channel ----
        if (tid < 3 * 66) {
            int r   = tid / 66;
            int col = tid % 66;
            int hh = h + r - 1, ww = col - 1;
            float v = 0.f;
            if (hh >= 0 && hh < 64 && ww >= 0 && ww < 64)
                v = x[(((size_t)(b * NC + c) * 64 + hh) << 6) + ww];
            xs[r][col] = v;
        }
        __syncthreads();
        // ---- materialize q[k][p] = s_i * s_j ----
        for (int idx = tid; idx < KT * 64; idx += 256) {
            int p = idx & 63, k = idx >> 6;
            int i, j;
            k_to_ij(k, i, j);
            float si = 1.f;
            if (i > 0) { int im = i - 1; si = xs[im / 3][p + im % 3]; }
            int jm = j - 1;
            float sj = xs[jm / 3][p + jm % 3];
            q[k][p] = si * sj;
        }
        __syncthreads();
        // ---- accumulate: acc[oi][pi] += Wt[c,k,o] * q[k][p] ----
        const float* wbase = Wt + (size_t)c * KT * NO;
        #pragma unroll 2
        for (int k = 0; k < KT; ++k) {
            const float4 w4 = *(const float4*)(wbase + (k << 6) + og * 4);
            const float4 q4 = *(const float4*)(&q[k][pg * 4]);
            const float wv[4] = {w4.x, w4.y, w4.z, w4.w};
            const float qv[4] = {q4.x, q4.y, q4.z, q4.w};
            #pragma unroll
            for (int oi = 0; oi < 4; ++oi)
                #pragma unroll
                for (int pi = 0; pi < 4; ++pi)
                    acc[oi][pi] += wv[oi] * qv[pi];
        }
    }

    // ---- epilogue: add bias, store float4 per owned o ----
    #pragma unroll
    for (int oi = 0; oi < 4; ++oi) {
        int o = og * 4 + oi;
        float bv = bias_eff[o];
        float4 r;
        r.x = acc[oi][0] + bv;
        r.y = acc[oi][1] + bv;
        r.z = acc[oi][2] + bv;
        r.w = acc[oi][3] + bv;
        *(float4*)&out[(((size_t)(b * NO + o) * 64 + h) << 6) + pg * 4] = r;
    }
}

extern "C" void kernel_launch(void* const* d_in, const int* in_sizes, int n_in,
                              void* d_out, int out_size, void* d_ws, size_t ws_size,
                              hipStream_t stream) {
    const float* x       = (const float*)d_in[0];
    const float* filters = (const float*)d_in[1];
    const float* biases  = (const float*)d_in[2];
    float* out = (float*)d_out;

    float* Wt       = (float*)d_ws;                 // 64*54*64 floats = 884736 B
    float* bias_eff = Wt + NC * KT * NO;            // +64 floats

    // symmetrize + transpose filters into workspace (runs every launch;
    // deterministic, ~0.2M threads, trivial cost)
    hipLaunchKernelGGL(prep_filters, dim3((NC * KT * NO) / 256), dim3(256), 0, stream,
                       filters, Wt);
    hipLaunchKernelGGL(prep_bias, dim3(1), dim3(64), 0, stream,
                       filters, biases, bias_eff);

    hipLaunchKernelGGL(poly2d_main, dim3(4 * 64), dim3(256), 0, stream,
                       x, Wt, bias_eff, out);
}

// Round 2
// 31.527 us; speedup vs baseline: 22.0084x; 22.0084x over previous
//
#include <hip/hip_runtime.h>

// Poly2d as bf16 MFMA GEMM.
// out[o, p] = sum_{c,k} W[o, c*56+k] * Q[c*56+k, p],  p = (b,h,w) pixel.
// Per channel, 56 terms: k=0..8 linear (s_j * (F0j+Fj0)), k=9..17 squares
// (s_j^2 * Fjj), k=18..53 pairs (s_i s_j * (Fij+Fji)), k=54 const-1 term
// (weight F00 + bias folded at c==0), k=55 zero pad.
// K_total = 64*56 = 3584 = 224 x 16  -> mfma_f32_32x32x16_bf16 tiles exactly.

typedef __attribute__((ext_vector_type(8))) short short8;
typedef __attribute__((ext_vector_type(16))) float f32x16;

#define NCH  64
#define NOUT 64

// term k -> (i, j) tables (i==0 means s_i == 1)
__device__ constexpr signed char TI[56] = {
  0,0,0,0,0,0,0,0,0,
  1,2,3,4,5,6,7,8,9,
  1,1,1,1,1,1,1,1,
  2,2,2,2,2,2,2,
  3,3,3,3,3,3,
  4,4,4,4,4,
  5,5,5,5,
  6,6,6,
  7,7,
  8,
  0,0};
__device__ constexpr signed char TJ[56] = {
  1,2,3,4,5,6,7,8,9,
  1,2,3,4,5,6,7,8,9,
  2,3,4,5,6,7,8,9,
  3,4,5,6,7,8,9,
  4,5,6,7,8,9,
  5,6,7,8,9,
  6,7,8,9,
  7,8,9,
  8,9,
  9,
  0,0};

__device__ __forceinline__ unsigned short f2bf(float f) {
  unsigned u = __float_as_uint(f);
  u += 0x7fffu + ((u >> 16) & 1u);          // RNE (inputs finite)
  return (unsigned short)(u >> 16);
}

// W2 layout (A-operand, coalesced per-wave 16B/lane loads):
//   elem idx = (((pair*7 + st)*2 + hf)*64 + o)*8 + e
//   sk = st*16 + hf*8 + e in [0,112) over channel pair; ch = pair*2 + (sk>=56)
__global__ __launch_bounds__(256) void prep_w2(const float* __restrict__ F,
                                               const float* __restrict__ biases,
                                               unsigned short* __restrict__ W2) {
  int idx = blockIdx.x * 256 + threadIdx.x;   // < 229376
  int e = idx & 7, o = (idx >> 3) & 63;
  int rest = idx >> 9;
  int hf = rest & 1, stp = rest >> 1;
  int st = stp % 7, pair = stp / 7;
  int sk = st * 16 + hf * 8 + e;
  int ch = pair * 2 + (sk >= 56 ? 1 : 0);
  int kl = sk >= 56 ? sk - 56 : sk;
  const float* base = F + (size_t)(o * NCH + ch) * 100;
  float w;
  if (kl < 54) {
    int i = TI[kl], j = TJ[kl];
    if (i == 0)      w = base[j] + base[j * 10];
    else if (i == j) w = base[i * 10 + j];
    else             w = base[i * 10 + j] + base[j * 10 + i];
  } else if (kl == 54) {
    w = base[0] + (ch == 0 ? biases[o] : 0.f);
  } else {
    w = 0.f;
  }
  W2[idx] = f2bf(w);
}

// 512 blocks = (4b * 64h) * 2 pixel-halves; 512 threads = 8 waves.
// Wave g owns channels [g*8, g*8+8), computes full 64o x 32p partial.
// Stage = 2 channels: xs stage -> Q materialize -> 7 MFMA k-steps.
__global__ __launch_bounds__(512, 4) void poly2d_mfma(
    const float* __restrict__ x, const unsigned short* __restrict__ W2,
    float* __restrict__ out) {
  const int blk = blockIdx.x;
  const int pt = blk & 1, bh = blk >> 1;
  const int b = bh >> 6, h = bh & 63;
  const int tid = threadIdx.x;
  const int lane = tid & 63, wave = tid >> 6;      // wave = k-group
  const int px = lane & 31, hf = lane >> 5;

  __shared__ float xs[16][3][34];                  // 16 ch x 3 rows x (32+halo)
  __shared__ unsigned short Q[8][32][128];         // 64 KB; 256B rows, XOR-swizzled

  f32x16 acc0, acc1;
  #pragma unroll
  for (int r = 0; r < 16; ++r) { acc0[r] = 0.f; acc1[r] = 0.f; }

  for (int stage = 0; stage < 4; ++stage) {
    __syncthreads();                               // prev MFMA reads done
    // ---- stage x rows for this stage's 16 channels (8 groups x 2) ----
    for (int idx = tid; idx < 16 * 102; idx += 512) {
      int c16 = idx / 102, r2 = idx % 102;
      int rr = r2 / 34, col = r2 % 34;
      int c = (c16 >> 1) * 8 + stage * 2 + (c16 & 1);
      int hh = h + rr - 1, ww = pt * 32 + col - 1;
      float v = 0.f;
      if (hh >= 0 && hh < 64 && (unsigned)ww < 64u)
        v = x[(((size_t)b * NCH + c) * 64 + hh) * 64 + ww];
      xs[c16][rr][col] = v;
    }
    __syncthreads();
    // ---- materialize Q: one (wave, chp=hf, px) per thread ----
    {
      const int c16 = wave * 2 + hf;
      float s[9];
      #pragma unroll
      for (int jm = 0; jm < 9; ++jm) s[jm] = xs[c16][jm / 3][px + jm % 3];
      char* qrow = (char*)&Q[wave][px][0];
      #pragma unroll
      for (int i = 0; i < 7; ++i) {
        unsigned pk[4];
        #pragma unroll
        for (int eo = 0; eo < 4; ++eo) {
          float qq[2];
          #pragma unroll
          for (int u = 0; u < 2; ++u) {
            const int k = i * 8 + eo * 2 + u;      // compile-time constant
            float v;
            if (k == 54)      v = 1.f;
            else if (k == 55) v = 0.f;
            else {
              float a = (TI[k] == 0) ? 1.f : s[TI[k] - 1];
              v = a * s[TJ[k] - 1];
            }
            qq[u] = v;
          }
          pk[eo] = (unsigned)f2bf(qq[0]) | ((unsigned)f2bf(qq[1]) << 16);
        }
        unsigned kbyte = (unsigned)(hf * 112 + i * 16);
        unsigned sw = kbyte ^ (unsigned)((px & 7) << 4);
        *(uint4*)(qrow + sw) = make_uint4(pk[0], pk[1], pk[2], pk[3]);
      }
    }
    __syncthreads();
    // ---- MFMA: 7 k-steps of 16 over this stage's 112-K slice ----
    const unsigned short* wbase =
        W2 + (size_t)(wave * 4 + stage) * 7168 + hf * 512 + px * 8;
    const char* qrow = (const char*)&Q[wave][px][0];
    #pragma unroll
    for (int st = 0; st < 7; ++st) {
      const short8 a0 = *(const short8*)(wbase + st * 1024);        // o 0..31
      const short8 a1 = *(const short8*)(wbase + st * 1024 + 256);  // o 32..63
      unsigned kbyte = (unsigned)(st * 32 + hf * 16);
      unsigned sw = kbyte ^ (unsigned)((px & 7) << 4);
      const short8 bq = *(const short8*)(qrow + sw);
      acc0 = __builtin_amdgcn_mfma_f32_32x32x16_bf16(a0, bq, acc0, 0, 0, 0);
      acc1 = __builtin_amdgcn_mfma_f32_32x32x16_bf16(a1, bq, acc1, 0, 0, 0);
    }
  }

  // ---- reduce 8 per-wave partials in LDS (aliases Q), store ----
  __syncthreads();
  float* R = (float*)&Q[0][0][0];                  // [8][64][32] f32 = 64 KB
  #pragma unroll
  for (int r = 0; r < 16; ++r) {
    int orow = (r & 3) + 8 * (r >> 2) + 4 * hf;    // D: col=lane&31, row formula (m74/m101)
    R[wave * 2048 + orow * 32 + px]        = acc0[r];
    R[wave * 2048 + (orow + 32) * 32 + px] = acc1[r];
  }
  __syncthreads();
  {
    int o = tid >> 3, p0 = (tid & 7) * 4;
    float4 sum = make_float4(0.f, 0.f, 0.f, 0.f);
    #pragma unroll
    for (int g = 0; g < 8; ++g) {
      float4 v = *(float4*)&R[g * 2048 + o * 32 + p0];
      sum.x += v.x; sum.y += v.y; sum.z += v.z; sum.w += v.w;
    }
    *(float4*)&out[(((size_t)b * NOUT + o) * 64 + h) * 64 + pt * 32 + p0] = sum;
  }
}

extern "C" void kernel_launch(void* const* d_in, const int* in_sizes, int n_in,
                              void* d_out, int out_size, void* d_ws, size_t ws_size,
                              hipStream_t stream) {
  const float* x       = (const float*)d_in[0];
  const float* filters = (const float*)d_in[1];
  const float* biases  = (const float*)d_in[2];
  float* out = (float*)d_out;
  unsigned short* W2 = (unsigned short*)d_ws;      // 229376 bf16 = 458752 B

  hipLaunchKernelGGL(prep_w2, dim3(896), dim3(256), 0, stream,
                     filters, biases, W2);
  hipLaunchKernelGGL(poly2d_mfma, dim3(512), dim3(512), 0, stream,
                     x, W2, out);
}

// Round 3
// 24.252 us; speedup vs baseline: 28.6100x; 1.3000x over previous
//
#include <hip/hip_runtime.h>
#include <hip/hip_bf16.h>

// Poly2d as bf16 MFMA GEMM, register-resident Q.
// out[o,p] = sum_{c,kl} W[o,c,kl] * Q[c,kl,p], kl in [0,56):
//   kl 0..8 linear (s_j*(F0j+Fj0)), 9..17 squares (s_j^2*Fjj),
//   18..53 pairs (s_i*s_j*(Fij+Fji)), 54 const-1 (F00 + bias @c==0), 55 zero.
//
// MFMA 32x32x16: lane (hf=l>>5, n=l&31) holds B[k=hf*8+e][n]. We choose the
// k-slot -> (channel,kl) bijection so each lane's slots use only channels
// cA = 2*pair+hf, cB = 2*pair+1-hf with compile-time kl:
//   step st<4 : ch = cA, kl = 16*st + e      (covers kl 0-7,16-23,32-39,48-55)
//   step st>=4: ch = cB, kl = 16*(st-4)+8+e  (covers kl 8-15,24-31,40-47)
// Union over hf covers both channels' kl 0..55 exactly once. W2 is written
// with the same permutation, so Q fragments are computed directly in VGPRs --
// no LDS staging, no barriers in the main loop.

typedef __attribute__((ext_vector_type(8))) short short8;
typedef __attribute__((ext_vector_type(16))) float f32x16;

#define NCH  64
#define NOUT 64

__device__ constexpr signed char TI[56] = {
  0,0,0,0,0,0,0,0,0,
  1,2,3,4,5,6,7,8,9,
  1,1,1,1,1,1,1,1,
  2,2,2,2,2,2,2,
  3,3,3,3,3,3,
  4,4,4,4,4,
  5,5,5,5,
  6,6,6,
  7,7,
  8,
  0,0};
__device__ constexpr signed char TJ[56] = {
  1,2,3,4,5,6,7,8,9,
  1,2,3,4,5,6,7,8,9,
  2,3,4,5,6,7,8,9,
  3,4,5,6,7,8,9,
  4,5,6,7,8,9,
  5,6,7,8,9,
  6,7,8,9,
  7,8,9,
  8,9,
  9,
  0,0};

__device__ __forceinline__ unsigned short f2bf(float f) {
  __hip_bfloat16 h = __float2bfloat16(f);
  unsigned short u;
  __builtin_memcpy(&u, &h, 2);
  return u;
}

// W2 flat layout: off = pair*7168 + st*1024 + hf*512 + o*8 + e   (shorts)
__global__ __launch_bounds__(256) void prep_w2(const float* __restrict__ F,
                                               const float* __restrict__ biases,
                                               unsigned short* __restrict__ W2) {
  int idx = blockIdx.x * 256 + threadIdx.x;   // < 229376
  int e = idx & 7, o = (idx >> 3) & 63;
  int rest = idx >> 9;                        // (pair*7+st)*2+hf
  int hf = rest & 1, stp = rest >> 1;
  int st = stp % 7, pair = stp / 7;
  int ch = (st < 4) ? (2 * pair + hf) : (2 * pair + 1 - hf);
  int kl = (st < 4) ? (16 * st + e) : (16 * (st - 4) + 8 + e);
  const float* base = F + (size_t)(o * NCH + ch) * 100;
  float w;
  if (kl < 54) {
    int i = TI[kl], j = TJ[kl];
    if (i == 0)      w = base[j] + base[j * 10];
    else if (i == j) w = base[i * 10 + j];
    else             w = base[i * 10 + j] + base[j * 10 + i];
  } else if (kl == 54) {
    w = base[0] + (ch == 0 ? biases[o] : 0.f);
  } else {
    w = 0.f;
  }
  W2[idx] = f2bf(w);
}

// 256 blocks = (b, h); 512 threads = 8 waves; wave w owns channels [8w, 8w+8).
// Each wave: 64o x 64px partial (4 MFMA tiles), K = 8ch*56 = 448 = 28 steps.
__global__ __launch_bounds__(512, 2) void poly2d_mfma(
    const float* __restrict__ x, const unsigned short* __restrict__ W2,
    float* __restrict__ out) {
  const int b = blockIdx.x >> 6, h = blockIdx.x & 63;
  const int tid = threadIdx.x;
  const int lane = tid & 63, wave = tid >> 6;
  const int px = lane & 31, hf = lane >> 5;

  __shared__ float xs[NCH][3][66];   // all channels, rows h-1..h+1, w -1..64
  __shared__ float R[8][64][32];     // split-K reduction, one pixel-half

  // ---- load all x rows once (zero-padded) ----
  #pragma unroll
  for (int it = 0; it < 25; ++it) {
    int idx = tid + it * 512;
    if (idx < NCH * 198) {
      int c = idx / 198, rem = idx % 198;
      int r = rem / 66, col = rem % 66;
      int hh = h + r - 1, ww = col - 1;
      float v = 0.f;
      if ((unsigned)hh < 64u && (unsigned)ww < 64u)
        v = x[(((size_t)b * NCH + c) * 64 + hh) * 64 + ww];
      xs[c][r][col] = v;
    }
  }
  __syncthreads();

  f32x16 a00, a01, a10, a11;
  #pragma unroll
  for (int r = 0; r < 16; ++r) { a00[r] = 0.f; a01[r] = 0.f; a10[r] = 0.f; a11[r] = 0.f; }

  auto computeP = [&](int cAl, int cBl, int pcol, short8* P) {
    float sA[9], sB[9];
    #pragma unroll
    for (int jm = 0; jm < 9; ++jm) {
      sA[jm] = xs[cAl][jm / 3][pcol + jm % 3];
      sB[jm] = xs[cBl][jm / 3][pcol + jm % 3];
    }
    #pragma unroll
    for (int g = 0; g < 7; ++g) {
      short8 pk;
      #pragma unroll
      for (int e = 0; e < 8; ++e) {
        const int kl = (g < 4) ? (16 * g + e) : (16 * (g - 4) + 8 + e);
        const float* s = (g < 4) ? sA : sB;
        float v;
        if (kl == 55)      v = 0.f;
        else if (kl == 54) v = 1.f;
        else if (kl < 9)   v = s[kl];
        else if (kl < 18)  { float t = s[kl - 9]; v = t * t; }
        else               v = s[TI[kl] - 1] * s[TJ[kl] - 1];
        pk[e] = (short)f2bf(v);
      }
      P[g] = pk;
    }
  };

  for (int stage = 0; stage < 4; ++stage) {
    const int cA = wave * 8 + stage * 2 + hf;   // base even -> cB = cA^1
    const int cB = cA ^ 1;
    short8 P0[7], P1[7];
    computeP(cA, cB, px, P0);          // pixel cols 0..31
    computeP(cA, cB, px + 32, P1);     // pixel cols 32..63
    const unsigned short* wb =
        W2 + (size_t)(wave * 4 + stage) * 7168 + hf * 512 + px * 8;
    #pragma unroll
    for (int st = 0; st < 7; ++st) {
      const short8 w0 = *(const short8*)(wb + st * 1024);        // o 0..31
      const short8 w1 = *(const short8*)(wb + st * 1024 + 256);  // o 32..63
      a00 = __builtin_amdgcn_mfma_f32_32x32x16_bf16(w0, P0[st], a00, 0, 0, 0);
      a10 = __builtin_amdgcn_mfma_f32_32x32x16_bf16(w1, P0[st], a10, 0, 0, 0);
      a01 = __builtin_amdgcn_mfma_f32_32x32x16_bf16(w0, P1[st], a01, 0, 0, 0);
      a11 = __builtin_amdgcn_mfma_f32_32x32x16_bf16(w1, P1[st], a11, 0, 0, 0);
    }
  }

  // ---- reduce 8 split-K partials; chunk = one pixel-half (64 KB LDS) ----
  // D layout (m74/m101): col = lane&31, row = (r&3) + 8*(r>>2) + 4*hf
  #pragma unroll
  for (int r = 0; r < 16; ++r) {
    int orow = (r & 3) + 8 * (r >> 2) + 4 * hf;
    R[wave][orow][px]      = a00[r];
    R[wave][orow + 32][px] = a10[r];
  }
  __syncthreads();
  {
    int o = tid >> 3, p4 = (tid & 7) * 4;
    float4 sum = make_float4(0.f, 0.f, 0.f, 0.f);
    #pragma unroll
    for (int g = 0; g < 8; ++g) {
      float4 v = *(float4*)&R[g][o][p4];
      sum.x += v.x; sum.y += v.y; sum.z += v.z; sum.w += v.w;
    }
    *(float4*)&out[(((size_t)b * NOUT + o) * 64 + h) * 64 + p4] = sum;
  }
  __syncthreads();
  #pragma unroll
  for (int r = 0; r < 16; ++r) {
    int orow = (r & 3) + 8 * (r >> 2) + 4 * hf;
    R[wave][orow][px]      = a01[r];
    R[wave][orow + 32][px] = a11[r];
  }
  __syncthreads();
  {
    int o = tid >> 3, p4 = (tid & 7) * 4;
    float4 sum = make_float4(0.f, 0.f, 0.f, 0.f);
    #pragma unroll
    for (int g = 0; g < 8; ++g) {
      float4 v = *(float4*)&R[g][o][p4];
      sum.x += v.x; sum.y += v.y; sum.z += v.z; sum.w += v.w;
    }
    *(float4*)&out[(((size_t)b * NOUT + o) * 64 + h) * 64 + 32 + p4] = sum;
  }
}

extern "C" void kernel_launch(void* const* d_in, const int* in_sizes, int n_in,
                              void* d_out, int out_size, void* d_ws, size_t ws_size,
                              hipStream_t stream) {
  const float* x       = (const float*)d_in[0];
  const float* filters = (const float*)d_in[1];
  const float* biases  = (const float*)d_in[2];
  float* out = (float*)d_out;
  unsigned short* W2 = (unsigned short*)d_ws;   // 229376 bf16 = 458752 B

  hipLaunchKernelGGL(prep_w2, dim3(896), dim3(256), 0, stream,
                     filters, biases, W2);
  hipLaunchKernelGGL(poly2d_mfma, dim3(256), dim3(512), 0, stream,
                     x, W2, out);
}

// Round 4
// 21.632 us; speedup vs baseline: 32.0756x; 1.1211x over previous
//
#include <hip/hip_runtime.h>
#include <hip/hip_bf16.h>

// Poly2d as bf16 MFMA GEMM, register-resident Q (see round-3 derivation).
// out[o,p] = sum_{c,kl} W[o,c,kl] * Q[c,kl,p], kl in [0,56):
//   kl 0..8 linear (s_j*(F0j+Fj0)), 9..17 squares (s_j^2*Fjj),
//   18..53 pairs (s_i*s_j*(Fij+Fji)), 54 const-1 (F00 + bias @c==0), 55 zero.
// MFMA 32x32x16 B-operand: lane (hf=l>>5, n=l&31) holds B[k=hf*8+e][n].
// k-slot -> (channel,kl) bijection chosen so each lane's slots use only
// channels cA = 2*pair+hf, cB = 2*pair+1-hf with compile-time kl:
//   step st<4 : ch = cA, kl = 16*st + e
//   step st>=4: ch = cB, kl = 16*(st-4)+8+e
// W2 is written with the same permutation (prep_w2), so Q fragments are
// computed directly in VGPRs -- no Q staging, no barriers in the main loop.

typedef __attribute__((ext_vector_type(8))) short short8;
typedef __attribute__((ext_vector_type(16))) float f32x16;

#define NCH  64
#define NOUT 64

__device__ constexpr signed char TI[56] = {
  0,0,0,0,0,0,0,0,0,
  1,2,3,4,5,6,7,8,9,
  1,1,1,1,1,1,1,1,
  2,2,2,2,2,2,2,
  3,3,3,3,3,3,
  4,4,4,4,4,
  5,5,5,5,
  6,6,6,
  7,7,
  8,
  0,0};
__device__ constexpr signed char TJ[56] = {
  1,2,3,4,5,6,7,8,9,
  1,2,3,4,5,6,7,8,9,
  2,3,4,5,6,7,8,9,
  3,4,5,6,7,8,9,
  4,5,6,7,8,9,
  5,6,7,8,9,
  6,7,8,9,
  7,8,9,
  8,9,
  9,
  0,0};

__device__ __forceinline__ unsigned short f2bf(float f) {
  __hip_bfloat16 h = __float2bfloat16(f);
  unsigned short u;
  __builtin_memcpy(&u, &h, 2);
  return u;
}

// W2 flat layout: off = pair*7168 + st*1024 + hf*512 + o*8 + e   (shorts)
__global__ __launch_bounds__(256) void prep_w2(const float* __restrict__ F,
                                               const float* __restrict__ biases,
                                               unsigned short* __restrict__ W2) {
  int idx = blockIdx.x * 256 + threadIdx.x;   // < 229376
  int e = idx & 7, o = (idx >> 3) & 63;
  int rest = idx >> 9;                        // (pair*7+st)*2+hf
  int hf = rest & 1, stp = rest >> 1;
  int st = stp % 7, pair = stp / 7;
  int ch = (st < 4) ? (2 * pair + hf) : (2 * pair + 1 - hf);
  int kl = (st < 4) ? (16 * st + e) : (16 * (st - 4) + 8 + e);
  const float* base = F + (size_t)(o * NCH + ch) * 100;
  float w;
  if (kl < 54) {
    int i = TI[kl], j = TJ[kl];
    if (i == 0)      w = base[j] + base[j * 10];
    else if (i == j) w = base[i * 10 + j];
    else             w = base[i * 10 + j] + base[j * 10 + i];
  } else if (kl == 54) {
    w = base[0] + (ch == 0 ? biases[o] : 0.f);
  } else {
    w = 0.f;
  }
  W2[idx] = f2bf(w);
}

// 256 blocks = (b, h); 512 threads = 8 waves; wave w owns channels [8w, 8w+8).
// LDS arena (136 KB), two phases:
//   phase 1 (xs): channel ci -> dwords [ci*216, ci*216+216): 3 rows x 72 cols,
//                 x[w] at col w+4; cols 0..3 and 68..71 are zero halo.
//                 Wave-private (wave w touches ci in [8w, 8w+8)) -> no barrier.
//   phase 2 (R):  partial sums, row (g*64+p) stride 68 dwords, o contiguous.
//                 Stride 68 => b128 reads/writes hit 8 lanes per 4-bank group
//                 (optimal 8 passes, no extra conflicts).
__global__ __launch_bounds__(512, 2) void poly2d_mfma(
    const float* __restrict__ x, const unsigned short* __restrict__ W2,
    float* __restrict__ out) {
  const int b = blockIdx.x >> 6, h = blockIdx.x & 63;
  const int tid = threadIdx.x;
  const int lane = tid & 63, wave = tid >> 6;
  const int px = lane & 31, hf = lane >> 5;

  __shared__ float smem[34816];   // 139264 B

  // ---- stage this wave's 8 channels (vectorized, division-free) ----
  {
    const int r = lane >> 4, q = lane & 15;          // lanes 0..47: body quads
    const size_t xbase = ((size_t)b * NCH + wave * 8) * 4096;
    #pragma unroll
    for (int i = 0; i < 8; ++i) {
      float* ch0 = &smem[(wave * 8 + i) * 216];
      if (lane < 48) {
        int hh = h + r - 1;
        bool ok = (unsigned)hh < 64u;
        int hcl = ok ? hh : 0;                       // clamped (safe) address
        float4 v = *(const float4*)&x[xbase + (size_t)i * 4096 + hcl * 64 + (q << 2)];
        if (!ok) v = make_float4(0.f, 0.f, 0.f, 0.f);
        *(float4*)&ch0[r * 72 + 4 + (q << 2)] = v;
      } else if (lane < 54) {
        int rr = (lane - 48) >> 1, side = lane & 1;  // zero halo cols
        *(float4*)&ch0[rr * 72 + (side ? 68 : 0)] = make_float4(0.f, 0.f, 0.f, 0.f);
      }
    }
  }
  // no __syncthreads: staging is wave-private, ordered by lgkmcnt

  f32x16 a00, a01, a10, a11;
  #pragma unroll
  for (int r = 0; r < 16; ++r) { a00[r] = 0.f; a01[r] = 0.f; a10[r] = 0.f; a11[r] = 0.f; }

  for (int stage = 0; stage < 4; ++stage) {
    const int cA = stage * 2 + hf;        // wave-local channel of this lane-half
    const int cB = cA ^ 1;
    const float* rA = &smem[(wave * 8 + cA) * 216 + px];
    const float* rB = &smem[(wave * 8 + cB) * 216 + px];
    // window values for both pixel halves; constant dword offsets from one
    // base per (channel,row) -> compiler pairs into ds_read2_b32
    float sA0[9], sA1[9], sB0[9], sB1[9];
    #pragma unroll
    for (int r = 0; r < 3; ++r) {
      #pragma unroll
      for (int d = 0; d < 3; ++d) {
        sA0[r * 3 + d] = rA[r * 72 + 3 + d];
        sA1[r * 3 + d] = rA[r * 72 + 35 + d];
        sB0[r * 3 + d] = rB[r * 72 + 3 + d];
        sB1[r * 3 + d] = rB[r * 72 + 35 + d];
      }
    }
    short8 P0[7], P1[7];
    #pragma unroll
    for (int g = 0; g < 7; ++g) {
      short8 p0, p1;
      #pragma unroll
      for (int e = 0; e < 8; ++e) {
        const int kl = (g < 4) ? (16 * g + e) : (16 * (g - 4) + 8 + e);
        const float* s0 = (g < 4) ? sA0 : sB0;
        const float* s1 = (g < 4) ? sA1 : sB1;
        float v0, v1;
        if (kl == 55)      { v0 = 0.f;   v1 = 0.f; }
        else if (kl == 54) { v0 = 1.f;   v1 = 1.f; }
        else if (kl < 9)   { v0 = s0[kl];           v1 = s1[kl]; }
        else if (kl < 18)  { float t0 = s0[kl - 9], t1 = s1[kl - 9];
                             v0 = t0 * t0;          v1 = t1 * t1; }
        else               { v0 = s0[TI[kl] - 1] * s0[TJ[kl] - 1];
                             v1 = s1[TI[kl] - 1] * s1[TJ[kl] - 1]; }
        p0[e] = (short)f2bf(v0);
        p1[e] = (short)f2bf(v1);
      }
      P0[g] = p0; P1[g] = p1;
    }
    const unsigned short* wb =
        W2 + (size_t)(wave * 4 + stage) * 7168 + hf * 512 + px * 8;
    #pragma unroll
    for (int st = 0; st < 7; ++st) {
      const short8 w0 = *(const short8*)(wb + st * 1024);        // o 0..31
      const short8 w1 = *(const short8*)(wb + st * 1024 + 256);  // o 32..63
      a00 = __builtin_amdgcn_mfma_f32_32x32x16_bf16(w0, P0[st], a00, 0, 0, 0);
      a10 = __builtin_amdgcn_mfma_f32_32x32x16_bf16(w1, P0[st], a10, 0, 0, 0);
      a01 = __builtin_amdgcn_mfma_f32_32x32x16_bf16(w0, P1[st], a01, 0, 0, 0);
      a11 = __builtin_amdgcn_mfma_f32_32x32x16_bf16(w1, P1[st], a11, 0, 0, 0);
    }
  }

  // ---- single-round transposed reduction over the 8 split-K partials ----
  __syncthreads();               // all waves done with xs (arena reused as R)
  // D layout (m74/m101): col = lane&31, row = (r&3) + 8*(r>>2) + 4*hf.
  // R(g, p, o) at smem[(g*64+p)*68 + o]; acc block r=4B..4B+3 -> o contiguous.
  {
    float* base0 = &smem[(wave * 64 + px) * 68];        // p = px
    float* base1 = &smem[(wave * 64 + px + 32) * 68];   // p = px+32
    #pragma unroll
    for (int blk = 0; blk < 4; ++blk) {
      int ob = blk * 8 + 4 * hf;
      *(float4*)&base0[ob]      = make_float4(a00[blk*4], a00[blk*4+1], a00[blk*4+2], a00[blk*4+3]);
      *(float4*)&base0[ob + 32] = make_float4(a10[blk*4], a10[blk*4+1], a10[blk*4+2], a10[blk*4+3]);
      *(float4*)&base1[ob]      = make_float4(a01[blk*4], a01[blk*4+1], a01[blk*4+2], a01[blk*4+3]);
      *(float4*)&base1[ob + 32] = make_float4(a11[blk*4], a11[blk*4+1], a11[blk*4+2], a11[blk*4+3]);
    }
  }
  __syncthreads();
  {
    const int op = wave * 8;     // this wave's o-block; lane = pixel p
    float s8[8] = {0.f, 0.f, 0.f, 0.f, 0.f, 0.f, 0.f, 0.f};
    #pragma unroll
    for (int g = 0; g < 8; ++g) {
      const float* rg = &smem[(g * 64 + lane) * 68 + op];
      float4 u0 = *(const float4*)&rg[0];
      float4 u1 = *(const float4*)&rg[4];
      s8[0] += u0.x; s8[1] += u0.y; s8[2] += u0.z; s8[3] += u0.w;
      s8[4] += u1.x; s8[5] += u1.y; s8[6] += u1.z; s8[7] += u1.w;
    }
    const size_t obase = (((size_t)b * NOUT + op) * 64 + h) * 64 + lane;
    #pragma unroll
    for (int k = 0; k < 8; ++k)
      out[obase + (size_t)k * 4096] = s8[k];
  }
}

extern "C" void kernel_launch(void* const* d_in, const int* in_sizes, int n_in,
                              void* d_out, int out_size, void* d_ws, size_t ws_size,
                              hipStream_t stream) {
  const float* x       = (const float*)d_in[0];
  const float* filters = (const float*)d_in[1];
  const float* biases  = (const float*)d_in[2];
  float* out = (float*)d_out;
  unsigned short* W2 = (unsigned short*)d_ws;   // 229376 bf16 = 458752 B

  hipLaunchKernelGGL(prep_w2, dim3(896), dim3(256), 0, stream,
                     filters, biases, W2);
  hipLaunchKernelGGL(poly2d_mfma, dim3(256), dim3(512), 0, stream,
                     x, W2, out);
}